// Round 6
// baseline (26693.500 us; speedup 1.0000x reference)
//
#include <hip/hip_runtime.h>
#include <math.h>

#define B_    32
#define S_    2048
#define DIN   256
#define H_    512
#define G_    2048
#define DOUT  256

#define NBLK   136
#define NPHASE 2050

typedef __attribute__((ext_vector_type(8))) short bf16x8;
typedef __attribute__((ext_vector_type(16))) float f32x16;

#define MFMA32(a,b,c) __builtin_amdgcn_mfma_f32_32x32x16_bf16((a),(b),(c),0,0,0)

// ---- ws byte offsets ----
#define OB_CTR       0u          // phase counters, 64B stride
#define OB_H0HI      147456u     // bf16 [2][32][512] per buffer
#define OB_H0LO      212992u
#define OB_H1HI      278528u
#define OB_H1LO      344064u
#define OB_STATE_END 409600u
#define OB_B0        409600u     // fp32 [2048] combined bias (packed cols)
#define OB_B1        417792u
#define OB_FHI       425984u     // bf16 [256][512]  Wfc^T split
#define OB_FLO       688128u
#define OB_W0HI      950272u     // bf16 [2048][768]  packed-col-major split
#define OB_W0LO      4096000u
#define OB_W1HI      7241728u    // bf16 [2048][1024]
#define OB_W1LO      11436032u
#define OB_END       15630336u

// ---- dynamic LDS layout (bytes) ----
#define LS_WHI   0
#define LS_WLO   65536
#define LS_PT    131072          // float[4][32][32]
#define LS_CST   147456          // float[256]
#define LS_TOTAL 148480

__device__ __forceinline__ float sigf(float v) { return 1.0f / (1.0f + expf(-v)); }

__device__ __forceinline__ unsigned short f2b(float f) {   // fp32 -> bf16 RNE
    union { float f; unsigned u; } v; v.f = f;
    unsigned r = v.u + 0x7fffu + ((v.u >> 16) & 1u);
    return (unsigned short)(r >> 16);
}
__device__ __forceinline__ float b2f(unsigned short h) {
    union { unsigned u; float f; } v; v.u = ((unsigned)h) << 16; return v.f;
}

// device-scope (cache-bypassing) state access
__device__ __forceinline__ unsigned long long ld64_coh(const unsigned short* p) {
    return __hip_atomic_load((const unsigned long long*)p,
                             __ATOMIC_RELAXED, __HIP_MEMORY_SCOPE_AGENT);
}
__device__ __forceinline__ void st32_coh(unsigned short* base, int soff, unsigned w) {
    __hip_atomic_store((unsigned*)(base + soff), w,
                       __ATOMIC_RELAXED, __HIP_MEMORY_SCOPE_AGENT);
}

union fragu { unsigned long long q[2]; bf16x8 v; };

// ---- repack: W -> packed-col-major split bf16 ----
__global__ __launch_bounds__(256) void repack_w(
    const float* __restrict__ s1, const float* __restrict__ s2,
    int k1, int K, int srcld, int dopack,
    unsigned short* __restrict__ hi, unsigned short* __restrict__ lo)
{
    const int p  = blockIdx.x;
    const int kk = blockIdx.y * 256 + threadIdx.x;
    if (kk >= K) return;
    const int oc = dopack ? ((((p >> 2) & 3) * H_) + ((p >> 4) << 2) + (p & 3)) : p;
    const float w = (kk < k1) ? s1[(size_t)kk * srcld + oc]
                              : s2[(size_t)(kk - k1) * srcld + oc];
    const unsigned short h = f2b(w);
    hi[(size_t)p * K + kk] = h;
    lo[(size_t)p * K + kk] = f2b(w - b2f(h));
}

__global__ __launch_bounds__(256) void repack_bias(
    const float* __restrict__ bx0, const float* __restrict__ bh0,
    const float* __restrict__ bx1, const float* __restrict__ bh1,
    char* __restrict__ wsb)
{
    const int q = blockIdx.x * 256 + threadIdx.x;
    if (q >= 2 * G_) return;
    const int p  = q & (G_ - 1);
    const int oc = (((p >> 2) & 3) * H_) + ((p >> 4) << 2) + (p & 3);
    float* dst = (float*)(wsb + (q < G_ ? OB_B0 : OB_B1));
    dst[p] = (q < G_) ? (bx0[oc] + bh0[oc]) : (bx1[oc] + bh1[oc]);
}

// ---- per-phase matmul body: batch all A loads, then MFMA ----
template<int ROLE, int NSTEP>
__device__ __forceinline__ void phase_mm(
    int k0, int colc, int halfl, int t,
    const float* __restrict__ x,
    const unsigned short* A0hi, const unsigned short* A0lo,
    const unsigned short* A1hi, const unsigned short* A1lo,
    const unsigned short* Whi,  const unsigned short* Wlo,
    f32x16& acc)
{
    fragu fh[NSTEP], fl[NSTEP];
    #pragma unroll
    for (int s = 0; s < NSTEP; ++s) {
        const int kf = k0 + s * 16;
        if (ROLE == 0 && kf < 256) {
            const float* xp = x + ((size_t)colc * S_ + t) * DIN + kf + halfl * 8;
            #pragma unroll
            for (int j = 0; j < 8; ++j) {
                const float v = xp[j];
                const unsigned short hh = f2b(v);
                fh[s].v[j] = (short)hh;
                fl[s].v[j] = (short)f2b(v - b2f(hh));
            }
        } else {
            const unsigned short *hi, *lo; int kk;
            if (ROLE == 0)      { hi = A1hi; lo = A1lo; kk = kf - 256; }
            else if (ROLE == 1) {
                if (kf < 512)   { hi = A0hi; lo = A0lo; kk = kf; }
                else            { hi = A1hi; lo = A1lo; kk = kf - 512; }
            } else              { hi = A0hi; lo = A0lo; kk = kf; }
            const int off = colc * 512 + kk + halfl * 8;
            fh[s].q[0] = ld64_coh(hi + off);
            fh[s].q[1] = ld64_coh(hi + off + 4);
            fl[s].q[0] = ld64_coh(lo + off);
            fl[s].q[1] = ld64_coh(lo + off + 4);
        }
    }
    #pragma unroll
    for (int s = 0; s < NSTEP; ++s) {
        const int k8a = ((k0 + s * 16) >> 3) + halfl;
        const bf16x8 bh = *(const bf16x8*)(Whi + (k8a * 32 + colc) * 8);
        const bf16x8 bl = *(const bf16x8*)(Wlo + (k8a * 32 + colc) * 8);
        acc = MFMA32(fh[s].v, bh, acc);
        acc = MFMA32(fl[s].v, bh, acc);
        acc = MFMA32(fh[s].v, bl, acc);
    }
}

// ---- persistent pipeline kernel ----
// blocks [0,64): layer0 t=p; [64,128): layer1 t=p-1; [128,136): FC t=p-2
__global__ __launch_bounds__(512, 2) void lstm_persist(
    const float* __restrict__ x, const float* __restrict__ bfc,
    float* __restrict__ out, char* __restrict__ wsb)
{
    extern __shared__ char smem[];
    unsigned short* Whi = (unsigned short*)(smem + LS_WHI);
    unsigned short* Wlo = (unsigned short*)(smem + LS_WLO);
    float* Pt   = (float*)(smem + LS_PT);
    float* cstL = (float*)(smem + LS_CST);
    unsigned* ctr = (unsigned*)wsb;

    const int blk = blockIdx.x, tid = threadIdx.x;
    const int wave = tid >> 6, lane = tid & 63;
    const int colc = lane & 31, halfl = lane >> 5;

    int role, bb;
    if (blk < 64)       { role = 0; bb = blk; }
    else if (blk < 128) { role = 1; bb = blk - 64; }
    else                { role = 2; bb = blk - 128; }

    const int K  = (role == 0) ? 768 : (role == 1 ? 1024 : 512);
    const int p0 = bb * 32;

    const unsigned short *WHIg, *WLOg;
    if (role == 0)      { WHIg = (const unsigned short*)(wsb + OB_W0HI); WLOg = (const unsigned short*)(wsb + OB_W0LO); }
    else if (role == 1) { WHIg = (const unsigned short*)(wsb + OB_W1HI); WLOg = (const unsigned short*)(wsb + OB_W1LO); }
    else                { WHIg = (const unsigned short*)(wsb + OB_FHI);  WLOg = (const unsigned short*)(wsb + OB_FLO); }

    // stage this block's weight slice into LDS once: [k8][32 cols][8]
    const int nk8 = K >> 3;
    for (int idx = tid; idx < nk8 * 32; idx += 512) {
        const int k8 = idx >> 5, cl = idx & 31;
        *(bf16x8*)(Whi + idx * 8) = *(const bf16x8*)(WHIg + (size_t)(p0 + cl) * K + k8 * 8);
        *(bf16x8*)(Wlo + idx * 8) = *(const bf16x8*)(WLOg + (size_t)(p0 + cl) * K + k8 * 8);
    }
    for (int i = tid; i < 256; i += 512) cstL[i] = 0.f;
    __syncthreads();

    unsigned short* H0HI = (unsigned short*)(wsb + OB_H0HI);
    unsigned short* H0LO = (unsigned short*)(wsb + OB_H0LO);
    unsigned short* H1HI = (unsigned short*)(wsb + OB_H1HI);
    unsigned short* H1LO = (unsigned short*)(wsb + OB_H1LO);
    const float* Bp = (const float*)(wsb + (role == 1 ? OB_B1 : OB_B0));

    const int k0 = wave * (K >> 3);

    for (int p = 0; p < NPHASE; ++p) {
        const int t = (role == 0) ? p : (role == 1 ? p - 1 : p - 2);
        if (t >= 0 && t < S_) {
            const int par_t = t & 1, par_tm = (t + 1) & 1;
            const unsigned short *A0hi = 0, *A0lo = 0, *A1hi = 0, *A1lo = 0;
            if (role == 0)      { A1hi = H0HI + par_tm * 16384; A1lo = H0LO + par_tm * 16384; }
            else if (role == 1) { A0hi = H0HI + par_t  * 16384; A0lo = H0LO + par_t  * 16384;
                                  A1hi = H1HI + par_tm * 16384; A1lo = H1LO + par_tm * 16384; }
            else                { A0hi = H1HI + par_t  * 16384; A0lo = H1LO + par_t  * 16384; }

            f32x16 acc;
            #pragma unroll
            for (int i = 0; i < 16; ++i) acc[i] = 0.f;

            if (role == 0)
                phase_mm<0, 6>(k0, colc, halfl, t, x, A0hi, A0lo, A1hi, A1lo, Whi, Wlo, acc);
            else if (role == 1)
                phase_mm<1, 8>(k0, colc, halfl, t, x, A0hi, A0lo, A1hi, A1lo, Whi, Wlo, acc);
            else
                phase_mm<2, 4>(k0, colc, halfl, t, x, A0hi, A0lo, A1hi, A1lo, Whi, Wlo, acc);

            // cross-wave reduce: waves 4-7 store, waves 0-3 accumulate
            if (wave >= 4) {
                #pragma unroll
                for (int rg = 0; rg < 16; ++rg) {
                    const int row = (rg & 3) + 8 * (rg >> 2) + 4 * halfl;
                    Pt[(wave - 4) * 1024 + row * 32 + colc] = acc[rg];
                }
            }
            __syncthreads();
            if (wave < 4) {
                #pragma unroll
                for (int rg = 0; rg < 16; ++rg) {
                    const int row = (rg & 3) + 8 * (rg >> 2) + 4 * halfl;
                    Pt[wave * 1024 + row * 32 + colc] += acc[rg];
                }
            }
            __syncthreads();

            if (role == 2) {
                #pragma unroll
                for (int ii = 0; ii < 2; ++ii) {
                    const int idx = tid * 2 + ii;
                    const int r = idx >> 5, c = idx & 31;
                    const float v = Pt[idx] + Pt[1024 + idx] + Pt[2048 + idx] + Pt[3072 + idx]
                                  + bfc[p0 + c];
                    out[((size_t)r * S_ + t) * DOUT + p0 + c] = v;
                }
            } else {
                #pragma unroll
                for (int ii = 0; ii < 2; ++ii) {
                    const int idx = tid * 2 + ii;
                    Pt[idx] = Pt[idx] + Pt[1024 + idx] + Pt[2048 + idx] + Pt[3072 + idx]
                            + Bp[p0 + (idx & 31)];
                }
                __syncthreads();
                if (tid < 128) {
                    const int r = tid >> 2, u2 = (tid & 3) * 2;      // units u2, u2+1
                    const int cb = ((u2 >> 2) << 4) + (u2 & 3);
                    unsigned short hh[2], hl[2];
                    #pragma unroll
                    for (int uu = 0; uu < 2; ++uu) {
                        const float fg = Pt[r * 32 + cb + uu + 0];
                        const float ig = Pt[r * 32 + cb + uu + 4];
                        const float gg = Pt[r * 32 + cb + uu + 8];
                        const float og = Pt[r * 32 + cb + uu + 12];
                        const float cv = cstL[r * 8 + u2 + uu];
                        const float cn = sigf(fg) * cv + sigf(ig) * tanhf(gg);
                        const float hn = sigf(og) * tanhf(cn);
                        cstL[r * 8 + u2 + uu] = cn;
                        hh[uu] = f2b(hn);
                        hl[uu] = f2b(hn - b2f(hh[uu]));
                    }
                    const unsigned whi = (unsigned)hh[0] | ((unsigned)hh[1] << 16);
                    const unsigned wlo = (unsigned)hl[0] | ((unsigned)hl[1] << 16);
                    const int soff = par_t * 16384 + r * 512 + bb * 8 + u2;   // even
                    if (role == 0) { st32_coh(H0HI, soff, whi); st32_coh(H0LO, soff, wlo); }
                    else           { st32_coh(H1HI, soff, whi); st32_coh(H1LO, soff, wlo); }
                }
            }
        }

        if (p < NPHASE - 1) {
            __syncthreads();          // drains each wave's vmem: sc1 stores are globally visible
            if (tid == 0) {
                __hip_atomic_fetch_add(&ctr[p * 16], 1u, __ATOMIC_RELAXED, __HIP_MEMORY_SCOPE_AGENT);
                while (__hip_atomic_load(&ctr[p * 16], __ATOMIC_RELAXED, __HIP_MEMORY_SCOPE_AGENT)
                       < (unsigned)NBLK)
                    __builtin_amdgcn_s_sleep(1);
            }
            __syncthreads();
        }
    }
}

extern "C" void kernel_launch(void* const* d_in, const int* in_sizes, int n_in,
                              void* d_out, int out_size, void* d_ws, size_t ws_size,
                              hipStream_t stream)
{
    const float* x   = (const float*)d_in[0];
    const float* Wx0 = (const float*)d_in[1];
    const float* bx0 = (const float*)d_in[2];
    const float* Wh0 = (const float*)d_in[3];
    const float* bh0 = (const float*)d_in[4];
    const float* Wx1 = (const float*)d_in[5];
    const float* bx1 = (const float*)d_in[6];
    const float* Wh1 = (const float*)d_in[7];
    const float* bh1 = (const float*)d_in[8];
    const float* Wfc = (const float*)d_in[9];
    const float* bfc = (const float*)d_in[10];
    float* out = (float*)d_out;
    char*  wsb = (char*)d_ws;

    // zero barrier counters + h state (runs inside the graph every replay;
    // blit-kernel end-of-dispatch release flushes zeros to the coherence point)
    hipMemsetAsync(d_ws, 0, OB_STATE_END, stream);

    repack_w<<<dim3(G_, 3), 256, 0, stream>>>(Wx0, Wh0, 256, 768, G_, 1,
        (unsigned short*)(wsb + OB_W0HI), (unsigned short*)(wsb + OB_W0LO));
    repack_w<<<dim3(G_, 4), 256, 0, stream>>>(Wx1, Wh1, 512, 1024, G_, 1,
        (unsigned short*)(wsb + OB_W1HI), (unsigned short*)(wsb + OB_W1LO));
    repack_w<<<dim3(DOUT, 2), 256, 0, stream>>>(Wfc, Wfc, 512, 512, DOUT, 0,
        (unsigned short*)(wsb + OB_FHI), (unsigned short*)(wsb + OB_FLO));
    repack_bias<<<16, 256, 0, stream>>>(bx0, bh0, bx1, bh1, wsb);

    hipFuncSetAttribute((const void*)lstm_persist,
                        hipFuncAttributeMaxDynamicSharedMemorySize, LS_TOTAL);
    lstm_persist<<<NBLK, 512, LS_TOTAL, stream>>>(x, bfc, out, wsb);
}

// Round 7
// 21153.259 us; speedup vs baseline: 1.2619x; 1.2619x over previous
//
#include <hip/hip_runtime.h>
#include <math.h>

#define B_    32
#define S_    2048
#define DIN   256
#define H_    512
#define G_    2048
#define DOUT  256

#define NBLK   136
#define NPHASE 2050

typedef __attribute__((ext_vector_type(8))) short bf16x8;
typedef __attribute__((ext_vector_type(16))) float f32x16;

#define MFMA32(a,b,c) __builtin_amdgcn_mfma_f32_32x32x16_bf16((a),(b),(c),0,0,0)

// ---- ws byte offsets ----
#define OB_SLOT      0u          // arrival slots, one u32 per block, 64B stride
#define OB_H0HI      147456u     // bf16 [2][32][512] per buffer
#define OB_H0LO      212992u
#define OB_H1HI      278528u
#define OB_H1LO      344064u
#define OB_STATE_END 409600u
#define OB_B0        409600u     // fp32 [2048] combined bias (packed cols)
#define OB_B1        417792u
#define OB_FHI       425984u     // bf16 [256][512]  Wfc^T split
#define OB_FLO       688128u
#define OB_W0HI      950272u     // bf16 [2048][768]  packed-col-major split
#define OB_W0LO      4096000u
#define OB_W1HI      7241728u    // bf16 [2048][1024]
#define OB_W1LO      11436032u
#define OB_END       15630336u
#define OB_XHI       15630336u   // bf16 [32][2048][256] x split
#define OB_XLO       49184768u
#define OB_XEND      82739200u

// ---- dynamic LDS layout (bytes) ----
#define LS_WHI   0
#define LS_WLO   65536
#define LS_PT    131072          // float[4][32][32]
#define LS_CST   147456          // float[256]
#define LS_TOTAL 148480

__device__ __forceinline__ float sigf(float v) { return 1.0f / (1.0f + expf(-v)); }

__device__ __forceinline__ unsigned short f2b(float f) {   // fp32 -> bf16 RNE
    union { float f; unsigned u; } v; v.f = f;
    unsigned r = v.u + 0x7fffu + ((v.u >> 16) & 1u);
    return (unsigned short)(r >> 16);
}
__device__ __forceinline__ float b2f(unsigned short h) {
    union { unsigned u; float f; } v; v.u = ((unsigned)h) << 16; return v.f;
}

// device-scope (cache-bypassing) state access
__device__ __forceinline__ unsigned long long ld64_coh(const unsigned short* p) {
    return __hip_atomic_load((const unsigned long long*)p,
                             __ATOMIC_RELAXED, __HIP_MEMORY_SCOPE_AGENT);
}
__device__ __forceinline__ void st32_coh(unsigned short* base, int soff, unsigned w) {
    __hip_atomic_store((unsigned*)(base + soff), w,
                       __ATOMIC_RELAXED, __HIP_MEMORY_SCOPE_AGENT);
}

union fragu { unsigned long long q[2]; bf16x8 v; };

// ---- repack: W -> packed-col-major split bf16 ----
__global__ __launch_bounds__(256) void repack_w(
    const float* __restrict__ s1, const float* __restrict__ s2,
    int k1, int K, int srcld, int dopack,
    unsigned short* __restrict__ hi, unsigned short* __restrict__ lo)
{
    const int p  = blockIdx.x;
    const int kk = blockIdx.y * 256 + threadIdx.x;
    if (kk >= K) return;
    const int oc = dopack ? ((((p >> 2) & 3) * H_) + ((p >> 4) << 2) + (p & 3)) : p;
    const float w = (kk < k1) ? s1[(size_t)kk * srcld + oc]
                              : s2[(size_t)(kk - k1) * srcld + oc];
    const unsigned short h = f2b(w);
    hi[(size_t)p * K + kk] = h;
    lo[(size_t)p * K + kk] = f2b(w - b2f(h));
}

__global__ __launch_bounds__(256) void repack_bias(
    const float* __restrict__ bx0, const float* __restrict__ bh0,
    const float* __restrict__ bx1, const float* __restrict__ bh1,
    char* __restrict__ wsb)
{
    const int q = blockIdx.x * 256 + threadIdx.x;
    if (q >= 2 * G_) return;
    const int p  = q & (G_ - 1);
    const int oc = (((p >> 2) & 3) * H_) + ((p >> 4) << 2) + (p & 3);
    float* dst = (float*)(wsb + (q < G_ ? OB_B0 : OB_B1));
    dst[p] = (q < G_) ? (bx0[oc] + bh0[oc]) : (bx1[oc] + bh1[oc]);
}

__global__ __launch_bounds__(256) void repack_x(const float* __restrict__ x, char* __restrict__ wsb)
{
    unsigned short* xhi = (unsigned short*)(wsb + OB_XHI);
    unsigned short* xlo = (unsigned short*)(wsb + OB_XLO);
    const size_t n = (size_t)B_ * S_ * DIN;
    for (size_t i = (size_t)blockIdx.x * 256 + threadIdx.x; i < n; i += (size_t)gridDim.x * 256) {
        const float v = x[i];
        const unsigned short h = f2b(v);
        xhi[i] = h;
        xlo[i] = f2b(v - b2f(h));
    }
}

// ---- per-phase matmul body: batch all A loads, then MFMA ----
template<int ROLE, int NSTEP>
__device__ __forceinline__ void phase_mm(
    int k0, int colc, int halfl, int t, int xsplit,
    const float* __restrict__ x,
    const unsigned short* __restrict__ XHI, const unsigned short* __restrict__ XLO,
    const unsigned short* A0hi, const unsigned short* A0lo,
    const unsigned short* A1hi, const unsigned short* A1lo,
    const unsigned short* Whi,  const unsigned short* Wlo,
    f32x16& acc)
{
    fragu fh[NSTEP], fl[NSTEP];
    #pragma unroll
    for (int s = 0; s < NSTEP; ++s) {
        const int kf = k0 + s * 16;
        if (ROLE == 0 && kf < 256) {
            const size_t o = ((size_t)colc * S_ + t) * DIN + kf + halfl * 8;
            if (xsplit) {
                fh[s].v = *(const bf16x8*)(XHI + o);
                fl[s].v = *(const bf16x8*)(XLO + o);
            } else {
                const float* xp = x + o;
                #pragma unroll
                for (int j = 0; j < 8; ++j) {
                    const float v = xp[j];
                    const unsigned short hh = f2b(v);
                    fh[s].v[j] = (short)hh;
                    fl[s].v[j] = (short)f2b(v - b2f(hh));
                }
            }
        } else {
            const unsigned short *hi, *lo; int kk;
            if (ROLE == 0)      { hi = A1hi; lo = A1lo; kk = kf - 256; }
            else if (ROLE == 1) {
                if (kf < 512)   { hi = A0hi; lo = A0lo; kk = kf; }
                else            { hi = A1hi; lo = A1lo; kk = kf - 512; }
            } else              { hi = A0hi; lo = A0lo; kk = kf; }
            const int off = colc * 512 + kk + halfl * 8;
            fh[s].q[0] = ld64_coh(hi + off);
            fh[s].q[1] = ld64_coh(hi + off + 4);
            fl[s].q[0] = ld64_coh(lo + off);
            fl[s].q[1] = ld64_coh(lo + off + 4);
        }
    }
    #pragma unroll
    for (int s = 0; s < NSTEP; ++s) {
        const int k8a = ((k0 + s * 16) >> 3) + halfl;
        const bf16x8 bh = *(const bf16x8*)(Whi + (k8a * 32 + colc) * 8);
        const bf16x8 bl = *(const bf16x8*)(Wlo + (k8a * 32 + colc) * 8);
        acc = MFMA32(fh[s].v, bh, acc);
        acc = MFMA32(fl[s].v, bh, acc);
        acc = MFMA32(fh[s].v, bl, acc);
    }
}

// ---- persistent pipeline kernel ----
// blocks [0,64): layer0 t=p; [64,128): layer1 t=p-1; [128,136): FC t=p-2
__global__ __launch_bounds__(512, 2) void lstm_persist(
    const float* __restrict__ x, const float* __restrict__ bfc,
    float* __restrict__ out, char* __restrict__ wsb, int xsplit)
{
    extern __shared__ char smem[];
    unsigned short* Whi = (unsigned short*)(smem + LS_WHI);
    unsigned short* Wlo = (unsigned short*)(smem + LS_WLO);
    float* Pt   = (float*)(smem + LS_PT);
    float* cstL = (float*)(smem + LS_CST);
    unsigned* slots = (unsigned*)(wsb + OB_SLOT);

    const int blk = blockIdx.x, tid = threadIdx.x;
    const int wave = tid >> 6, lane = tid & 63;
    const int colc = lane & 31, halfl = lane >> 5;

    int role, bb;
    if (blk < 64)       { role = 0; bb = blk; }
    else if (blk < 128) { role = 1; bb = blk - 64; }
    else                { role = 2; bb = blk - 128; }

    const int K  = (role == 0) ? 768 : (role == 1 ? 1024 : 512);
    const int p0 = bb * 32;

    const unsigned short *WHIg, *WLOg;
    if (role == 0)      { WHIg = (const unsigned short*)(wsb + OB_W0HI); WLOg = (const unsigned short*)(wsb + OB_W0LO); }
    else if (role == 1) { WHIg = (const unsigned short*)(wsb + OB_W1HI); WLOg = (const unsigned short*)(wsb + OB_W1LO); }
    else                { WHIg = (const unsigned short*)(wsb + OB_FHI);  WLOg = (const unsigned short*)(wsb + OB_FLO); }

    // stage this block's weight slice into LDS once: [k8][32 cols][8]
    const int nk8 = K >> 3;
    for (int idx = tid; idx < nk8 * 32; idx += 512) {
        const int k8 = idx >> 5, cl = idx & 31;
        *(bf16x8*)(Whi + idx * 8) = *(const bf16x8*)(WHIg + (size_t)(p0 + cl) * K + k8 * 8);
        *(bf16x8*)(Wlo + idx * 8) = *(const bf16x8*)(WLOg + (size_t)(p0 + cl) * K + k8 * 8);
    }
    for (int i = tid; i < 256; i += 512) cstL[i] = 0.f;
    __syncthreads();

    unsigned short* H0HI = (unsigned short*)(wsb + OB_H0HI);
    unsigned short* H0LO = (unsigned short*)(wsb + OB_H0LO);
    unsigned short* H1HI = (unsigned short*)(wsb + OB_H1HI);
    unsigned short* H1LO = (unsigned short*)(wsb + OB_H1LO);
    const unsigned short* XHI = (const unsigned short*)(wsb + OB_XHI);
    const unsigned short* XLO = (const unsigned short*)(wsb + OB_XLO);
    const float* Bp = (const float*)(wsb + (role == 1 ? OB_B1 : OB_B0));

    const int k0 = wave * (K >> 3);

    for (int p = 0; p < NPHASE; ++p) {
        const int t = (role == 0) ? p : (role == 1 ? p - 1 : p - 2);
        if (t >= 0 && t < S_) {
            const int par_t = t & 1, par_tm = (t + 1) & 1;
            const unsigned short *A0hi = 0, *A0lo = 0, *A1hi = 0, *A1lo = 0;
            if (role == 0)      { A1hi = H0HI + par_tm * 16384; A1lo = H0LO + par_tm * 16384; }
            else if (role == 1) { A0hi = H0HI + par_t  * 16384; A0lo = H0LO + par_t  * 16384;
                                  A1hi = H1HI + par_tm * 16384; A1lo = H1LO + par_tm * 16384; }
            else                { A0hi = H1HI + par_t  * 16384; A0lo = H1LO + par_t  * 16384; }

            f32x16 acc;
            #pragma unroll
            for (int i = 0; i < 16; ++i) acc[i] = 0.f;

            if (role == 0)
                phase_mm<0, 6>(k0, colc, halfl, t, xsplit, x, XHI, XLO,
                               A0hi, A0lo, A1hi, A1lo, Whi, Wlo, acc);
            else if (role == 1)
                phase_mm<1, 8>(k0, colc, halfl, t, xsplit, x, XHI, XLO,
                               A0hi, A0lo, A1hi, A1lo, Whi, Wlo, acc);
            else
                phase_mm<2, 4>(k0, colc, halfl, t, xsplit, x, XHI, XLO,
                               A0hi, A0lo, A1hi, A1lo, Whi, Wlo, acc);

            // cross-wave reduce: waves 4-7 store, waves 0-3 accumulate
            if (wave >= 4) {
                #pragma unroll
                for (int rg = 0; rg < 16; ++rg) {
                    const int row = (rg & 3) + 8 * (rg >> 2) + 4 * halfl;
                    Pt[(wave - 4) * 1024 + row * 32 + colc] = acc[rg];
                }
            }
            __syncthreads();
            if (wave < 4) {
                #pragma unroll
                for (int rg = 0; rg < 16; ++rg) {
                    const int row = (rg & 3) + 8 * (rg >> 2) + 4 * halfl;
                    Pt[wave * 1024 + row * 32 + colc] += acc[rg];
                }
            }
            __syncthreads();

            if (role == 2) {
                #pragma unroll
                for (int ii = 0; ii < 2; ++ii) {
                    const int idx = tid * 2 + ii;
                    const int r = idx >> 5, c = idx & 31;
                    const float v = Pt[idx] + Pt[1024 + idx] + Pt[2048 + idx] + Pt[3072 + idx]
                                  + bfc[p0 + c];
                    out[((size_t)r * S_ + t) * DOUT + p0 + c] = v;
                }
            } else {
                #pragma unroll
                for (int ii = 0; ii < 2; ++ii) {
                    const int idx = tid * 2 + ii;
                    Pt[idx] = Pt[idx] + Pt[1024 + idx] + Pt[2048 + idx] + Pt[3072 + idx]
                            + Bp[p0 + (idx & 31)];
                }
                __syncthreads();
                if (tid < 128) {
                    const int r = tid >> 2, u2 = (tid & 3) * 2;      // units u2, u2+1
                    const int cb = ((u2 >> 2) << 4) + (u2 & 3);
                    unsigned short hh[2], hl[2];
                    #pragma unroll
                    for (int uu = 0; uu < 2; ++uu) {
                        const float fg = Pt[r * 32 + cb + uu + 0];
                        const float ig = Pt[r * 32 + cb + uu + 4];
                        const float gg = Pt[r * 32 + cb + uu + 8];
                        const float og = Pt[r * 32 + cb + uu + 12];
                        const float cv = cstL[r * 8 + u2 + uu];
                        const float cn = sigf(fg) * cv + sigf(ig) * tanhf(gg);
                        const float hn = sigf(og) * tanhf(cn);
                        cstL[r * 8 + u2 + uu] = cn;
                        hh[uu] = f2b(hn);
                        hl[uu] = f2b(hn - b2f(hh[uu]));
                    }
                    const unsigned whi = (unsigned)hh[0] | ((unsigned)hh[1] << 16);
                    const unsigned wlo = (unsigned)hl[0] | ((unsigned)hl[1] << 16);
                    const int soff = par_t * 16384 + r * 512 + bb * 8 + u2;   // even
                    if (role == 0) { st32_coh(H0HI, soff, whi); st32_coh(H0LO, soff, wlo); }
                    else           { st32_coh(H1HI, soff, whi); st32_coh(H1LO, soff, wlo); }
                }
            }
        }

        // ---- contention-free barrier: slot store + poll (wave 0 only) ----
        if (p < NPHASE - 1) {
            __syncthreads();           // all waves' state stores drained (vmcnt 0)
            if (tid < 64) {
                const unsigned tgt = (unsigned)(p + 1);
                if (tid == 0)
                    __hip_atomic_store(&slots[blk * 16], tgt,
                                       __ATOMIC_RELAXED, __HIP_MEMORY_SCOPE_AGENT);
                for (;;) {
                    bool ok = true;
                    #pragma unroll
                    for (int j = 0; j < 3; ++j) {
                        const int s = tid + j * 64;
                        if (s < NBLK) {
                            const unsigned v = __hip_atomic_load(&slots[s * 16],
                                               __ATOMIC_RELAXED, __HIP_MEMORY_SCOPE_AGENT);
                            ok = ok && (v >= tgt);
                        }
                    }
                    if (__all(ok)) break;
                    __builtin_amdgcn_s_sleep(1);
                }
            }
            __syncthreads();
        }
    }
}

extern "C" void kernel_launch(void* const* d_in, const int* in_sizes, int n_in,
                              void* d_out, int out_size, void* d_ws, size_t ws_size,
                              hipStream_t stream)
{
    const float* x   = (const float*)d_in[0];
    const float* Wx0 = (const float*)d_in[1];
    const float* bx0 = (const float*)d_in[2];
    const float* Wh0 = (const float*)d_in[3];
    const float* bh0 = (const float*)d_in[4];
    const float* Wx1 = (const float*)d_in[5];
    const float* bx1 = (const float*)d_in[6];
    const float* Wh1 = (const float*)d_in[7];
    const float* bh1 = (const float*)d_in[8];
    const float* Wfc = (const float*)d_in[9];
    const float* bfc = (const float*)d_in[10];
    float* out = (float*)d_out;
    char*  wsb = (char*)d_ws;

    const int xsplit = (ws_size >= OB_XEND) ? 1 : 0;

    // zero slots + h state (runs inside the graph every replay)
    hipMemsetAsync(d_ws, 0, OB_STATE_END, stream);

    repack_w<<<dim3(G_, 3), 256, 0, stream>>>(Wx0, Wh0, 256, 768, G_, 1,
        (unsigned short*)(wsb + OB_W0HI), (unsigned short*)(wsb + OB_W0LO));
    repack_w<<<dim3(G_, 4), 256, 0, stream>>>(Wx1, Wh1, 512, 1024, G_, 1,
        (unsigned short*)(wsb + OB_W1HI), (unsigned short*)(wsb + OB_W1LO));
    repack_w<<<dim3(DOUT, 2), 256, 0, stream>>>(Wfc, Wfc, 512, 512, DOUT, 0,
        (unsigned short*)(wsb + OB_FHI), (unsigned short*)(wsb + OB_FLO));
    repack_bias<<<16, 256, 0, stream>>>(bx0, bh0, bx1, bh1, wsb);
    if (xsplit) repack_x<<<2048, 256, 0, stream>>>(x, wsb);

    hipFuncSetAttribute((const void*)lstm_persist,
                        hipFuncAttributeMaxDynamicSharedMemorySize, LS_TOTAL);
    lstm_persist<<<NBLK, 512, LS_TOTAL, stream>>>(x, bfc, out, wsb, xsplit);
}

// Round 8
// 15294.209 us; speedup vs baseline: 1.7453x; 1.3831x over previous
//
#include <hip/hip_runtime.h>
#include <math.h>

#define B_    32
#define S_    2048
#define DIN   256
#define H_    512
#define G_    2048
#define DOUT  256

#define NBLK   136
#define NPHASE 2050

typedef __attribute__((ext_vector_type(8))) short bf16x8;
typedef __attribute__((ext_vector_type(16))) float f32x16;

#define MFMA32(a,b,c) __builtin_amdgcn_mfma_f32_32x32x16_bf16((a),(b),(c),0,0,0)

// ---- ws byte offsets ----
#define OB_SLOT      0u          // arrival slots, one u32 per block, 64B stride
#define OB_REL       16384u      // 9 release lines, 64B stride
#define OB_H0HI      147456u     // bf16 [2][32][512] per buffer
#define OB_H0LO      212992u
#define OB_H1HI      278528u
#define OB_H1LO      344064u
#define OB_STATE_END 409600u
#define OB_B0        409600u     // fp32 [2048] combined bias (packed cols)
#define OB_B1        417792u
#define OB_FHI       425984u     // bf16 [256][512]  Wfc^T split
#define OB_FLO       688128u
#define OB_W0HI      950272u     // bf16 [2048][768]  packed-col-major split
#define OB_W0LO      4096000u
#define OB_W1HI      7241728u    // bf16 [2048][1024]
#define OB_W1LO      11436032u
#define OB_END       15630336u
#define OB_XHI       15630336u   // bf16 [32][2048][256] x split
#define OB_XLO       49184768u
#define OB_XEND      82739200u

// ---- dynamic LDS layout (bytes) ----
#define LS_WHI   0
#define LS_WLO   65536
#define LS_PT    131072          // float[4][32][32]
#define LS_CST   147456          // float[256]
#define LS_TOTAL 148480

__device__ __forceinline__ float sigf(float v) { return 1.0f / (1.0f + expf(-v)); }

__device__ __forceinline__ unsigned short f2b(float f) {   // fp32 -> bf16 RNE
    union { float f; unsigned u; } v; v.f = f;
    unsigned r = v.u + 0x7fffu + ((v.u >> 16) & 1u);
    return (unsigned short)(r >> 16);
}
__device__ __forceinline__ float b2f(unsigned short h) {
    union { unsigned u; float f; } v; v.u = ((unsigned)h) << 16; return v.f;
}

// 16B uncached (coherence-point) load: bypasses L1/L2 via sc0 sc1.
// NO waitcnt here — caller must drain vmcnt before consuming.
__device__ __forceinline__ bf16x8 ld128_coh(const unsigned short* p) {
    bf16x8 r;
    asm volatile("global_load_dwordx4 %0, %1, off sc0 sc1"
                 : "=v"(r) : "v"(p) : "memory");
    return r;
}
__device__ __forceinline__ void st32_coh(unsigned short* base, int soff, unsigned w) {
    __hip_atomic_store((unsigned*)(base + soff), w,
                       __ATOMIC_RELAXED, __HIP_MEMORY_SCOPE_AGENT);
}

// ---- repack: W -> packed-col-major split bf16 ----
__global__ __launch_bounds__(256) void repack_w(
    const float* __restrict__ s1, const float* __restrict__ s2,
    int k1, int K, int srcld, int dopack,
    unsigned short* __restrict__ hi, unsigned short* __restrict__ lo)
{
    const int p  = blockIdx.x;
    const int kk = blockIdx.y * 256 + threadIdx.x;
    if (kk >= K) return;
    const int oc = dopack ? ((((p >> 2) & 3) * H_) + ((p >> 4) << 2) + (p & 3)) : p;
    const float w = (kk < k1) ? s1[(size_t)kk * srcld + oc]
                              : s2[(size_t)(kk - k1) * srcld + oc];
    const unsigned short h = f2b(w);
    hi[(size_t)p * K + kk] = h;
    lo[(size_t)p * K + kk] = f2b(w - b2f(h));
}

__global__ __launch_bounds__(256) void repack_bias(
    const float* __restrict__ bx0, const float* __restrict__ bh0,
    const float* __restrict__ bx1, const float* __restrict__ bh1,
    char* __restrict__ wsb)
{
    const int q = blockIdx.x * 256 + threadIdx.x;
    if (q >= 2 * G_) return;
    const int p  = q & (G_ - 1);
    const int oc = (((p >> 2) & 3) * H_) + ((p >> 4) << 2) + (p & 3);
    float* dst = (float*)(wsb + (q < G_ ? OB_B0 : OB_B1));
    dst[p] = (q < G_) ? (bx0[oc] + bh0[oc]) : (bx1[oc] + bh1[oc]);
}

__global__ __launch_bounds__(256) void repack_x(const float* __restrict__ x, char* __restrict__ wsb)
{
    unsigned short* xhi = (unsigned short*)(wsb + OB_XHI);
    unsigned short* xlo = (unsigned short*)(wsb + OB_XLO);
    const size_t n = (size_t)B_ * S_ * DIN;
    for (size_t i = (size_t)blockIdx.x * 256 + threadIdx.x; i < n; i += (size_t)gridDim.x * 256) {
        const float v = x[i];
        const unsigned short h = f2b(v);
        xhi[i] = h;
        xlo[i] = f2b(v - b2f(h));
    }
}

// ---- per-phase matmul body: batch all A loads (16B uncached), drain, MFMA ----
template<int ROLE, int NSTEP>
__device__ __forceinline__ void phase_mm(
    int k0, int colc, int halfl, int t, int xsplit,
    const float* __restrict__ x,
    const unsigned short* __restrict__ XHI, const unsigned short* __restrict__ XLO,
    const unsigned short* A0hi, const unsigned short* A0lo,
    const unsigned short* A1hi, const unsigned short* A1lo,
    const unsigned short* Whi,  const unsigned short* Wlo,
    f32x16& acc)
{
    bf16x8 fh[NSTEP], fl[NSTEP];
    #pragma unroll
    for (int s = 0; s < NSTEP; ++s) {
        const int kf = k0 + s * 16;
        if (ROLE == 0 && kf < 256) {
            const size_t o = ((size_t)colc * S_ + t) * DIN + kf + halfl * 8;
            if (xsplit) {
                fh[s] = *(const bf16x8*)(XHI + o);
                fl[s] = *(const bf16x8*)(XLO + o);
            } else {
                const float* xp = x + o;
                #pragma unroll
                for (int j = 0; j < 8; ++j) {
                    const float v = xp[j];
                    const unsigned short hh = f2b(v);
                    fh[s][j] = (short)hh;
                    fl[s][j] = (short)f2b(v - b2f(hh));
                }
            }
        } else {
            const unsigned short *hi, *lo; int kk;
            if (ROLE == 0)      { hi = A1hi; lo = A1lo; kk = kf - 256; }
            else if (ROLE == 1) {
                if (kf < 512)   { hi = A0hi; lo = A0lo; kk = kf; }
                else            { hi = A1hi; lo = A1lo; kk = kf - 512; }
            } else              { hi = A0hi; lo = A0lo; kk = kf; }
            const int off = colc * 512 + kk + halfl * 8;
            fh[s] = ld128_coh(hi + off);
            fl[s] = ld128_coh(lo + off);
        }
    }
    // drain the async uncached loads; pin MFMAs after the wait (rule #18)
    asm volatile("s_waitcnt vmcnt(0)" ::: "memory");
    __builtin_amdgcn_sched_barrier(0);

    #pragma unroll
    for (int s = 0; s < NSTEP; ++s) {
        const int k8a = ((k0 + s * 16) >> 3) + halfl;
        const bf16x8 bh = *(const bf16x8*)(Whi + (k8a * 32 + colc) * 8);
        const bf16x8 bl = *(const bf16x8*)(Wlo + (k8a * 32 + colc) * 8);
        acc = MFMA32(fh[s], bh, acc);
        acc = MFMA32(fl[s], bh, acc);
        acc = MFMA32(fh[s], bl, acc);
    }
}

// ---- persistent pipeline kernel ----
// blocks [0,64): layer0 t=p; [64,128): layer1 t=p-1; [128,136): FC t=p-2
__global__ __launch_bounds__(512, 2) void lstm_persist(
    const float* __restrict__ x, const float* __restrict__ bfc,
    float* __restrict__ out, char* __restrict__ wsb, int xsplit)
{
    extern __shared__ char smem[];
    unsigned short* Whi = (unsigned short*)(smem + LS_WHI);
    unsigned short* Wlo = (unsigned short*)(smem + LS_WLO);
    float* Pt   = (float*)(smem + LS_PT);
    float* cstL = (float*)(smem + LS_CST);
    unsigned* slots = (unsigned*)(wsb + OB_SLOT);
    unsigned* rel   = (unsigned*)(wsb + OB_REL);

    const int blk = blockIdx.x, tid = threadIdx.x;
    const int wave = tid >> 6, lane = tid & 63;
    const int colc = lane & 31, halfl = lane >> 5;

    int role, bb;
    if (blk < 64)       { role = 0; bb = blk; }
    else if (blk < 128) { role = 1; bb = blk - 64; }
    else                { role = 2; bb = blk - 128; }

    const int K  = (role == 0) ? 768 : (role == 1 ? 1024 : 512);
    const int p0 = bb * 32;

    const unsigned short *WHIg, *WLOg;
    if (role == 0)      { WHIg = (const unsigned short*)(wsb + OB_W0HI); WLOg = (const unsigned short*)(wsb + OB_W0LO); }
    else if (role == 1) { WHIg = (const unsigned short*)(wsb + OB_W1HI); WLOg = (const unsigned short*)(wsb + OB_W1LO); }
    else                { WHIg = (const unsigned short*)(wsb + OB_FHI);  WLOg = (const unsigned short*)(wsb + OB_FLO); }

    // stage this block's weight slice into LDS once: [k8][32 cols][8]
    const int nk8 = K >> 3;
    for (int idx = tid; idx < nk8 * 32; idx += 512) {
        const int k8 = idx >> 5, cl = idx & 31;
        *(bf16x8*)(Whi + idx * 8) = *(const bf16x8*)(WHIg + (size_t)(p0 + cl) * K + k8 * 8);
        *(bf16x8*)(Wlo + idx * 8) = *(const bf16x8*)(WLOg + (size_t)(p0 + cl) * K + k8 * 8);
    }
    for (int i = tid; i < 256; i += 512) cstL[i] = 0.f;
    __syncthreads();

    unsigned short* H0HI = (unsigned short*)(wsb + OB_H0HI);
    unsigned short* H0LO = (unsigned short*)(wsb + OB_H0LO);
    unsigned short* H1HI = (unsigned short*)(wsb + OB_H1HI);
    unsigned short* H1LO = (unsigned short*)(wsb + OB_H1LO);
    const unsigned short* XHI = (const unsigned short*)(wsb + OB_XHI);
    const unsigned short* XLO = (const unsigned short*)(wsb + OB_XLO);
    const float* Bp = (const float*)(wsb + (role == 1 ? OB_B1 : OB_B0));

    const int k0 = wave * (K >> 3);

    for (int p = 0; p < NPHASE; ++p) {
        const int t = (role == 0) ? p : (role == 1 ? p - 1 : p - 2);
        if (t >= 0 && t < S_) {
            const int par_t = t & 1, par_tm = (t + 1) & 1;
            const unsigned short *A0hi = 0, *A0lo = 0, *A1hi = 0, *A1lo = 0;
            if (role == 0)      { A1hi = H0HI + par_tm * 16384; A1lo = H0LO + par_tm * 16384; }
            else if (role == 1) { A0hi = H0HI + par_t  * 16384; A0lo = H0LO + par_t  * 16384;
                                  A1hi = H1HI + par_tm * 16384; A1lo = H1LO + par_tm * 16384; }
            else                { A0hi = H1HI + par_t  * 16384; A0lo = H1LO + par_t  * 16384; }

            f32x16 acc;
            #pragma unroll
            for (int i = 0; i < 16; ++i) acc[i] = 0.f;

            if (role == 0)
                phase_mm<0, 6>(k0, colc, halfl, t, xsplit, x, XHI, XLO,
                               A0hi, A0lo, A1hi, A1lo, Whi, Wlo, acc);
            else if (role == 1)
                phase_mm<1, 8>(k0, colc, halfl, t, xsplit, x, XHI, XLO,
                               A0hi, A0lo, A1hi, A1lo, Whi, Wlo, acc);
            else
                phase_mm<2, 4>(k0, colc, halfl, t, xsplit, x, XHI, XLO,
                               A0hi, A0lo, A1hi, A1lo, Whi, Wlo, acc);

            // cross-wave reduce: waves 4-7 store, waves 0-3 accumulate
            if (wave >= 4) {
                #pragma unroll
                for (int rg = 0; rg < 16; ++rg) {
                    const int row = (rg & 3) + 8 * (rg >> 2) + 4 * halfl;
                    Pt[(wave - 4) * 1024 + row * 32 + colc] = acc[rg];
                }
            }
            __syncthreads();
            if (wave < 4) {
                #pragma unroll
                for (int rg = 0; rg < 16; ++rg) {
                    const int row = (rg & 3) + 8 * (rg >> 2) + 4 * halfl;
                    Pt[wave * 1024 + row * 32 + colc] += acc[rg];
                }
            }
            __syncthreads();

            if (role == 2) {
                #pragma unroll
                for (int ii = 0; ii < 2; ++ii) {
                    const int idx = tid * 2 + ii;
                    const int r = idx >> 5, c = idx & 31;
                    const float v = Pt[idx] + Pt[1024 + idx] + Pt[2048 + idx] + Pt[3072 + idx]
                                  + bfc[p0 + c];
                    out[((size_t)r * S_ + t) * DOUT + p0 + c] = v;
                }
            } else {
                #pragma unroll
                for (int ii = 0; ii < 2; ++ii) {
                    const int idx = tid * 2 + ii;
                    Pt[idx] = Pt[idx] + Pt[1024 + idx] + Pt[2048 + idx] + Pt[3072 + idx]
                            + Bp[p0 + (idx & 31)];
                }
                __syncthreads();
                if (tid < 128) {
                    const int r = tid >> 2, u2 = (tid & 3) * 2;      // units u2, u2+1
                    const int cb = ((u2 >> 2) << 4) + (u2 & 3);
                    unsigned short hh[2], hl[2];
                    #pragma unroll
                    for (int uu = 0; uu < 2; ++uu) {
                        const float fg = Pt[r * 32 + cb + uu + 0];
                        const float ig = Pt[r * 32 + cb + uu + 4];
                        const float gg = Pt[r * 32 + cb + uu + 8];
                        const float og = Pt[r * 32 + cb + uu + 12];
                        const float cv = cstL[r * 8 + u2 + uu];
                        const float cn = sigf(fg) * cv + sigf(ig) * tanhf(gg);
                        const float hn = sigf(og) * tanhf(cn);
                        cstL[r * 8 + u2 + uu] = cn;
                        hh[uu] = f2b(hn);
                        hl[uu] = f2b(hn - b2f(hh[uu]));
                    }
                    const unsigned whi = (unsigned)hh[0] | ((unsigned)hh[1] << 16);
                    const unsigned wlo = (unsigned)hl[0] | ((unsigned)hl[1] << 16);
                    const int soff = par_t * 16384 + r * 512 + bb * 8 + u2;   // even
                    if (role == 0) { st32_coh(H0HI, soff, whi); st32_coh(H0LO, soff, wlo); }
                    else           { st32_coh(H1HI, soff, whi); st32_coh(H1LO, soff, wlo); }
                }
            }
        }

        // ---- hierarchical barrier: slot stores -> block0 aggregates -> 9-line release ----
        if (p < NPHASE - 1) {
            __syncthreads();           // all waves' state stores drained (vmcnt 0)
            const unsigned tgt = (unsigned)(p + 1);
            if (tid == 0)
                __hip_atomic_store(&slots[blk * 16], tgt,
                                   __ATOMIC_RELAXED, __HIP_MEMORY_SCOPE_AGENT);
            if (blk == 0 && tid < 64) {
                for (;;) {
                    bool ok = true;
                    #pragma unroll
                    for (int j = 0; j < 3; ++j) {
                        const int s = tid + j * 64;
                        if (s < NBLK) {
                            const unsigned v = __hip_atomic_load(&slots[s * 16],
                                               __ATOMIC_RELAXED, __HIP_MEMORY_SCOPE_AGENT);
                            ok = ok && (v >= tgt);
                        }
                    }
                    if (__all(ok)) break;
                    __builtin_amdgcn_s_sleep(2);
                }
                if (tid < 9)
                    __hip_atomic_store(&rel[tid * 16], tgt,
                                       __ATOMIC_RELAXED, __HIP_MEMORY_SCOPE_AGENT);
            }
            if (tid < 64) {
                const int g = blk >> 4;      // 0..8; all 64 lanes poll ONE address
                while (__hip_atomic_load(&rel[g * 16],
                       __ATOMIC_RELAXED, __HIP_MEMORY_SCOPE_AGENT) < tgt)
                    __builtin_amdgcn_s_sleep(2);
            }
            __syncthreads();
        }
    }
}

extern "C" void kernel_launch(void* const* d_in, const int* in_sizes, int n_in,
                              void* d_out, int out_size, void* d_ws, size_t ws_size,
                              hipStream_t stream)
{
    const float* x   = (const float*)d_in[0];
    const float* Wx0 = (const float*)d_in[1];
    const float* bx0 = (const float*)d_in[2];
    const float* Wh0 = (const float*)d_in[3];
    const float* bh0 = (const float*)d_in[4];
    const float* Wx1 = (const float*)d_in[5];
    const float* bx1 = (const float*)d_in[6];
    const float* Wh1 = (const float*)d_in[7];
    const float* bh1 = (const float*)d_in[8];
    const float* Wfc = (const float*)d_in[9];
    const float* bfc = (const float*)d_in[10];
    float* out = (float*)d_out;
    char*  wsb = (char*)d_ws;

    const int xsplit = (ws_size >= OB_XEND) ? 1 : 0;

    // zero slots + release lines + h state (runs inside the graph every replay)
    hipMemsetAsync(d_ws, 0, OB_STATE_END, stream);

    repack_w<<<dim3(G_, 3), 256, 0, stream>>>(Wx0, Wh0, 256, 768, G_, 1,
        (unsigned short*)(wsb + OB_W0HI), (unsigned short*)(wsb + OB_W0LO));
    repack_w<<<dim3(G_, 4), 256, 0, stream>>>(Wx1, Wh1, 512, 1024, G_, 1,
        (unsigned short*)(wsb + OB_W1HI), (unsigned short*)(wsb + OB_W1LO));
    repack_w<<<dim3(DOUT, 2), 256, 0, stream>>>(Wfc, Wfc, 512, 512, DOUT, 0,
        (unsigned short*)(wsb + OB_FHI), (unsigned short*)(wsb + OB_FLO));
    repack_bias<<<16, 256, 0, stream>>>(bx0, bh0, bx1, bh1, wsb);
    if (xsplit) repack_x<<<2048, 256, 0, stream>>>(x, wsb);

    hipFuncSetAttribute((const void*)lstm_persist,
                        hipFuncAttributeMaxDynamicSharedMemorySize, LS_TOTAL);
    lstm_persist<<<NBLK, 512, LS_TOTAL, stream>>>(x, bfc, out, wsb, xsplit);
}

// Round 9
// 13774.977 us; speedup vs baseline: 1.9378x; 1.1103x over previous
//
#include <hip/hip_runtime.h>
#include <math.h>

#define B_    32
#define S_    2048
#define DIN   256
#define H_    512
#define G_    2048
#define DOUT  256

#define NBLK  136
#define T_    2048

typedef __attribute__((ext_vector_type(8))) short bf16x8;
typedef __attribute__((ext_vector_type(16))) float f32x16;

#define MFMA32(a,b,c) __builtin_amdgcn_mfma_f32_32x32x16_bf16((a),(b),(c),0,0,0)

// ---- ws byte offsets ----
#define OB_SLOT      0u          // 136 progress slots (int), 64B stride
#define OB_H0HI      16384u      // bf16 [4][32][512] (4-deep ring)
#define OB_H0LO      147456u
#define OB_H1HI      278528u
#define OB_H1LO      409600u
#define OB_STATE_END 540672u
#define OB_B0        540672u     // fp32 [2048] combined bias (packed cols)
#define OB_B1        548864u
#define OB_FHI       557056u     // bf16 [256][512]  Wfc^T split
#define OB_FLO       819200u
#define OB_W0HI      1081344u    // bf16 [2048][768]  packed-col-major split
#define OB_W0LO      4227072u
#define OB_W1HI      7372800u    // bf16 [2048][1024]
#define OB_W1LO      11567104u
#define OB_END       15761408u
#define OB_XHI       15761408u   // bf16 [32][2048][256] x split
#define OB_XLO       49315840u
#define OB_XEND      82870272u

// ---- dynamic LDS layout (bytes) ----
#define LS_WHI   0
#define LS_WLO   65536
#define LS_PT    131072          // float[4][32][32]
#define LS_CST   147456          // float[256]
#define LS_TOTAL 148480

__device__ __forceinline__ float sigf(float v) { return 1.0f / (1.0f + expf(-v)); }

__device__ __forceinline__ unsigned short f2b(float f) {   // fp32 -> bf16 RNE
    union { float f; unsigned u; } v; v.f = f;
    unsigned r = v.u + 0x7fffu + ((v.u >> 16) & 1u);
    return (unsigned short)(r >> 16);
}
__device__ __forceinline__ float b2f(unsigned short h) {
    union { unsigned u; float f; } v; v.u = ((unsigned)h) << 16; return v.f;
}

// 16B uncached (coherence-point) load: bypasses L1/L2 via sc0 sc1.
// NO waitcnt here — caller must drain vmcnt before consuming.
__device__ __forceinline__ bf16x8 ld128_coh(const unsigned short* p) {
    bf16x8 r;
    asm volatile("global_load_dwordx4 %0, %1, off sc0 sc1"
                 : "=v"(r) : "v"(p) : "memory");
    return r;
}
__device__ __forceinline__ void st32_coh(unsigned short* base, int soff, unsigned w) {
    __hip_atomic_store((unsigned*)(base + soff), w,
                       __ATOMIC_RELAXED, __HIP_MEMORY_SCOPE_AGENT);
}
__device__ __forceinline__ int ld_slot(const int* slots, int i) {
    return __hip_atomic_load(&slots[i * 16], __ATOMIC_RELAXED, __HIP_MEMORY_SCOPE_AGENT);
}

// ---- repack: W -> packed-col-major split bf16 ----
__global__ __launch_bounds__(256) void repack_w(
    const float* __restrict__ s1, const float* __restrict__ s2,
    int k1, int K, int srcld, int dopack,
    unsigned short* __restrict__ hi, unsigned short* __restrict__ lo)
{
    const int p  = blockIdx.x;
    const int kk = blockIdx.y * 256 + threadIdx.x;
    if (kk >= K) return;
    const int oc = dopack ? ((((p >> 2) & 3) * H_) + ((p >> 4) << 2) + (p & 3)) : p;
    const float w = (kk < k1) ? s1[(size_t)kk * srcld + oc]
                              : s2[(size_t)(kk - k1) * srcld + oc];
    const unsigned short h = f2b(w);
    hi[(size_t)p * K + kk] = h;
    lo[(size_t)p * K + kk] = f2b(w - b2f(h));
}

__global__ __launch_bounds__(256) void repack_bias(
    const float* __restrict__ bx0, const float* __restrict__ bh0,
    const float* __restrict__ bx1, const float* __restrict__ bh1,
    char* __restrict__ wsb)
{
    const int q = blockIdx.x * 256 + threadIdx.x;
    if (q >= 2 * G_) return;
    const int p  = q & (G_ - 1);
    const int oc = (((p >> 2) & 3) * H_) + ((p >> 4) << 2) + (p & 3);
    float* dst = (float*)(wsb + (q < G_ ? OB_B0 : OB_B1));
    dst[p] = (q < G_) ? (bx0[oc] + bh0[oc]) : (bx1[oc] + bh1[oc]);
}

__global__ __launch_bounds__(256) void repack_x(const float* __restrict__ x, char* __restrict__ wsb)
{
    unsigned short* xhi = (unsigned short*)(wsb + OB_XHI);
    unsigned short* xlo = (unsigned short*)(wsb + OB_XLO);
    const size_t n = (size_t)B_ * S_ * DIN;
    for (size_t i = (size_t)blockIdx.x * 256 + threadIdx.x; i < n; i += (size_t)gridDim.x * 256) {
        const float v = x[i];
        const unsigned short h = f2b(v);
        xhi[i] = h;
        xlo[i] = f2b(v - b2f(h));
    }
}

// ---- per-phase matmul body: batch all A loads (16B uncached), drain, MFMA ----
template<int ROLE, int NSTEP>
__device__ __forceinline__ void phase_mm(
    int k0, int colc, int halfl, int t, int xsplit,
    const float* __restrict__ x,
    const unsigned short* __restrict__ XHI, const unsigned short* __restrict__ XLO,
    const unsigned short* A0hi, const unsigned short* A0lo,
    const unsigned short* A1hi, const unsigned short* A1lo,
    const unsigned short* Whi,  const unsigned short* Wlo,
    f32x16& acc)
{
    bf16x8 fh[NSTEP], fl[NSTEP];
    #pragma unroll
    for (int s = 0; s < NSTEP; ++s) {
        const int kf = k0 + s * 16;
        if (ROLE == 0 && kf < 256) {
            const size_t o = ((size_t)colc * S_ + t) * DIN + kf + halfl * 8;
            if (xsplit) {
                fh[s] = *(const bf16x8*)(XHI + o);
                fl[s] = *(const bf16x8*)(XLO + o);
            } else {
                const float* xp = x + o;
                #pragma unroll
                for (int j = 0; j < 8; ++j) {
                    const float v = xp[j];
                    const unsigned short hh = f2b(v);
                    fh[s][j] = (short)hh;
                    fl[s][j] = (short)f2b(v - b2f(hh));
                }
            }
        } else {
            const unsigned short *hi, *lo; int kk;
            if (ROLE == 0)      { hi = A1hi; lo = A1lo; kk = kf - 256; }
            else if (ROLE == 1) {
                if (kf < 512)   { hi = A0hi; lo = A0lo; kk = kf; }
                else            { hi = A1hi; lo = A1lo; kk = kf - 512; }
            } else              { hi = A0hi; lo = A0lo; kk = kf; }
            const int off = colc * 512 + kk + halfl * 8;
            fh[s] = ld128_coh(hi + off);
            fl[s] = ld128_coh(lo + off);
        }
    }
    // drain the async uncached loads; pin MFMAs after the wait (rule #18)
    asm volatile("s_waitcnt vmcnt(0)" ::: "memory");
    __builtin_amdgcn_sched_barrier(0);

    #pragma unroll
    for (int s = 0; s < NSTEP; ++s) {
        const int k8a = ((k0 + s * 16) >> 3) + halfl;
        const bf16x8 bh = *(const bf16x8*)(Whi + (k8a * 32 + colc) * 8);
        const bf16x8 bl = *(const bf16x8*)(Wlo + (k8a * 32 + colc) * 8);
        acc = MFMA32(fh[s], bh, acc);
        acc = MFMA32(fl[s], bh, acc);
        acc = MFMA32(fh[s], bl, acc);
    }
}

// ---- persistent dataflow kernel ----
// blocks [0,64): layer0; [64,128): layer1; [128,136): FC.  All loop t=0..2047.
// slots[i] = timesteps completed by block i (monotone).
__global__ __launch_bounds__(512, 2) void lstm_persist(
    const float* __restrict__ x, const float* __restrict__ bfc,
    float* __restrict__ out, char* __restrict__ wsb, int xsplit)
{
    extern __shared__ char smem[];
    unsigned short* Whi = (unsigned short*)(smem + LS_WHI);
    unsigned short* Wlo = (unsigned short*)(smem + LS_WLO);
    float* Pt   = (float*)(smem + LS_PT);
    float* cstL = (float*)(smem + LS_CST);
    int* slots  = (int*)(wsb + OB_SLOT);

    const int blk = blockIdx.x, tid = threadIdx.x;
    const int wave = tid >> 6, lane = tid & 63;
    const int colc = lane & 31, halfl = lane >> 5;

    int role, bb;
    if (blk < 64)       { role = 0; bb = blk; }
    else if (blk < 128) { role = 1; bb = blk - 64; }
    else                { role = 2; bb = blk - 128; }

    const int K  = (role == 0) ? 768 : (role == 1 ? 1024 : 512);
    const int p0 = bb * 32;

    const unsigned short *WHIg, *WLOg;
    if (role == 0)      { WHIg = (const unsigned short*)(wsb + OB_W0HI); WLOg = (const unsigned short*)(wsb + OB_W0LO); }
    else if (role == 1) { WHIg = (const unsigned short*)(wsb + OB_W1HI); WLOg = (const unsigned short*)(wsb + OB_W1LO); }
    else                { WHIg = (const unsigned short*)(wsb + OB_FHI);  WLOg = (const unsigned short*)(wsb + OB_FLO); }

    // stage this block's weight slice into LDS once: [k8][32 cols][8]
    const int nk8 = K >> 3;
    for (int idx = tid; idx < nk8 * 32; idx += 512) {
        const int k8 = idx >> 5, cl = idx & 31;
        *(bf16x8*)(Whi + idx * 8) = *(const bf16x8*)(WHIg + (size_t)(p0 + cl) * K + k8 * 8);
        *(bf16x8*)(Wlo + idx * 8) = *(const bf16x8*)(WLOg + (size_t)(p0 + cl) * K + k8 * 8);
    }
    for (int i = tid; i < 256; i += 512) cstL[i] = 0.f;
    __syncthreads();

    unsigned short* H0HI = (unsigned short*)(wsb + OB_H0HI);
    unsigned short* H0LO = (unsigned short*)(wsb + OB_H0LO);
    unsigned short* H1HI = (unsigned short*)(wsb + OB_H1HI);
    unsigned short* H1LO = (unsigned short*)(wsb + OB_H1LO);
    const unsigned short* XHI = (const unsigned short*)(wsb + OB_XHI);
    const unsigned short* XLO = (const unsigned short*)(wsb + OB_XLO);
    const float* Bp = (const float*)(wsb + (role == 1 ? OB_B1 : OB_B0));

    const int k0 = wave * (K >> 3);

    // register-cached progress values (slots are monotone)
    int sA = 0, sB = 0, sC = 0;

    for (int t = 0; t < T_; ++t) {
        // ---- dataflow wait (wave 0 polls; register caching skips satisfied slots) ----
        if (tid < 64) {
            if (role == 0) {
                const int tA = t, tB = t - 3;              // own L0 >= t, L1 >= t-3
                for (;;) {
                    bool ok = true;
                    if (sA < tA) sA = ld_slot(slots, lane);
                    ok = ok && (sA >= tA);
                    if (sB < tB) sB = ld_slot(slots, 64 + lane);
                    ok = ok && (sB >= tB);
                    if (__all(ok)) break;
                    __builtin_amdgcn_s_sleep(4);
                }
            } else if (role == 1) {
                const int tA = t + 1, tB = t, tC = t - 3;  // L0 >= t+1, own >= t, FC >= t-3
                for (;;) {
                    bool ok = true;
                    if (sA < tA) sA = ld_slot(slots, lane);
                    ok = ok && (sA >= tA);
                    if (sB < tB) sB = ld_slot(slots, 64 + lane);
                    ok = ok && (sB >= tB);
                    if (lane < 8) {
                        if (sC < tC) sC = ld_slot(slots, 128 + lane);
                        ok = ok && (sC >= tC);
                    }
                    if (__all(ok)) break;
                    __builtin_amdgcn_s_sleep(4);
                }
            } else {
                const int tA = t + 1;                      // L1 >= t+1
                for (;;) {
                    bool ok = true;
                    if (sA < tA) sA = ld_slot(slots, 64 + lane);
                    ok = ok && (sA >= tA);
                    if (__all(ok)) break;
                    __builtin_amdgcn_s_sleep(4);
                }
            }
        }
        __syncthreads();

        // ---- ring-buffer pointers for this t ----
        const int pw = t & 3, pr = (t - 1) & 3;
        const unsigned short *A0hi = 0, *A0lo = 0, *A1hi = 0, *A1lo = 0;
        if (role == 0)      { A1hi = H0HI + pr * 16384; A1lo = H0LO + pr * 16384; }
        else if (role == 1) { A0hi = H0HI + pw * 16384; A0lo = H0LO + pw * 16384;
                              A1hi = H1HI + pr * 16384; A1lo = H1LO + pr * 16384; }
        else                { A0hi = H1HI + pw * 16384; A0lo = H1LO + pw * 16384; }

        f32x16 acc;
        #pragma unroll
        for (int i = 0; i < 16; ++i) acc[i] = 0.f;

        if (role == 0)
            phase_mm<0, 6>(k0, colc, halfl, t, xsplit, x, XHI, XLO,
                           A0hi, A0lo, A1hi, A1lo, Whi, Wlo, acc);
        else if (role == 1)
            phase_mm<1, 8>(k0, colc, halfl, t, xsplit, x, XHI, XLO,
                           A0hi, A0lo, A1hi, A1lo, Whi, Wlo, acc);
        else
            phase_mm<2, 4>(k0, colc, halfl, t, xsplit, x, XHI, XLO,
                           A0hi, A0lo, A1hi, A1lo, Whi, Wlo, acc);

        // cross-wave reduce: waves 4-7 store, waves 0-3 accumulate
        if (wave >= 4) {
            #pragma unroll
            for (int rg = 0; rg < 16; ++rg) {
                const int row = (rg & 3) + 8 * (rg >> 2) + 4 * halfl;
                Pt[(wave - 4) * 1024 + row * 32 + colc] = acc[rg];
            }
        }
        __syncthreads();
        if (wave < 4) {
            #pragma unroll
            for (int rg = 0; rg < 16; ++rg) {
                const int row = (rg & 3) + 8 * (rg >> 2) + 4 * halfl;
                Pt[wave * 1024 + row * 32 + colc] += acc[rg];
            }
        }
        __syncthreads();

        if (role == 2) {
            #pragma unroll
            for (int ii = 0; ii < 2; ++ii) {
                const int idx = tid * 2 + ii;
                const int r = idx >> 5, c = idx & 31;
                const float v = Pt[idx] + Pt[1024 + idx] + Pt[2048 + idx] + Pt[3072 + idx]
                              + bfc[p0 + c];
                out[((size_t)r * S_ + t) * DOUT + p0 + c] = v;
            }
        } else {
            #pragma unroll
            for (int ii = 0; ii < 2; ++ii) {
                const int idx = tid * 2 + ii;
                Pt[idx] = Pt[idx] + Pt[1024 + idx] + Pt[2048 + idx] + Pt[3072 + idx]
                        + Bp[p0 + (idx & 31)];
            }
            __syncthreads();
            if (tid < 128) {
                const int r = tid >> 2, u2 = (tid & 3) * 2;      // units u2, u2+1
                const int cb = ((u2 >> 2) << 4) + (u2 & 3);
                unsigned short hh[2], hl[2];
                #pragma unroll
                for (int uu = 0; uu < 2; ++uu) {
                    const float fg = Pt[r * 32 + cb + uu + 0];
                    const float ig = Pt[r * 32 + cb + uu + 4];
                    const float gg = Pt[r * 32 + cb + uu + 8];
                    const float og = Pt[r * 32 + cb + uu + 12];
                    const float cv = cstL[r * 8 + u2 + uu];
                    const float cn = sigf(fg) * cv + sigf(ig) * tanhf(gg);
                    const float hn = sigf(og) * tanhf(cn);
                    cstL[r * 8 + u2 + uu] = cn;
                    hh[uu] = f2b(hn);
                    hl[uu] = f2b(hn - b2f(hh[uu]));
                }
                const unsigned whi = (unsigned)hh[0] | ((unsigned)hh[1] << 16);
                const unsigned wlo = (unsigned)hl[0] | ((unsigned)hl[1] << 16);
                const int soff = pw * 16384 + r * 512 + bb * 8 + u2;   // even
                if (role == 0) { st32_coh(H0HI, soff, whi); st32_coh(H0LO, soff, wlo); }
                else           { st32_coh(H1HI, soff, whi); st32_coh(H1LO, soff, wlo); }
            }
        }

        // ---- publish progress (stores drained by the syncthreads below) ----
        __syncthreads();
        if (tid == 0)
            __hip_atomic_store(&slots[blk * 16], t + 1,
                               __ATOMIC_RELAXED, __HIP_MEMORY_SCOPE_AGENT);
    }
}

extern "C" void kernel_launch(void* const* d_in, const int* in_sizes, int n_in,
                              void* d_out, int out_size, void* d_ws, size_t ws_size,
                              hipStream_t stream)
{
    const float* x   = (const float*)d_in[0];
    const float* Wx0 = (const float*)d_in[1];
    const float* bx0 = (const float*)d_in[2];
    const float* Wh0 = (const float*)d_in[3];
    const float* bh0 = (const float*)d_in[4];
    const float* Wx1 = (const float*)d_in[5];
    const float* bx1 = (const float*)d_in[6];
    const float* Wh1 = (const float*)d_in[7];
    const float* bh1 = (const float*)d_in[8];
    const float* Wfc = (const float*)d_in[9];
    const float* bfc = (const float*)d_in[10];
    float* out = (float*)d_out;
    char*  wsb = (char*)d_ws;

    const int xsplit = (ws_size >= OB_XEND) ? 1 : 0;

    // zero slots + h rings (runs inside the graph every replay)
    hipMemsetAsync(d_ws, 0, OB_STATE_END, stream);

    repack_w<<<dim3(G_, 3), 256, 0, stream>>>(Wx0, Wh0, 256, 768, G_, 1,
        (unsigned short*)(wsb + OB_W0HI), (unsigned short*)(wsb + OB_W0LO));
    repack_w<<<dim3(G_, 4), 256, 0, stream>>>(Wx1, Wh1, 512, 1024, G_, 1,
        (unsigned short*)(wsb + OB_W1HI), (unsigned short*)(wsb + OB_W1LO));
    repack_w<<<dim3(DOUT, 2), 256, 0, stream>>>(Wfc, Wfc, 512, 512, DOUT, 0,
        (unsigned short*)(wsb + OB_FHI), (unsigned short*)(wsb + OB_FLO));
    repack_bias<<<16, 256, 0, stream>>>(bx0, bh0, bx1, bh1, wsb);
    if (xsplit) repack_x<<<2048, 256, 0, stream>>>(x, wsb);

    hipFuncSetAttribute((const void*)lstm_persist,
                        hipFuncAttributeMaxDynamicSharedMemorySize, LS_TOTAL);
    lstm_persist<<<NBLK, 512, LS_TOTAL, stream>>>(x, bfc, out, wsb, xsplit);
}